// Round 1
// baseline (1059.351 us; speedup 1.0000x reference)
//
#include <hip/hip_runtime.h>
#include <math.h>

// clDice loss: sigmoid + dice + 10x soft-skeletonize (min3x3 -> max3x3 -> blend -> clip)
// on 32x1x512x512 pred & target, then skeleton dice. Output: [loss, dice, skel_dice].

#define H 512
#define W 512
#define IMG (H * W)        // 262144 = 1<<18
#define NIMG 64            // 32 pred images + 32 target images stacked
#define NPRED 32
#define ITERS 10

#define SPITCH 72          // LDS row pitch (floats): 4 left halo + 64 + 4 right (keeps 16B alignment)
#define SROWS 68           // 2 + 64 + 2

__device__ __forceinline__ float wsum(float v) {
#pragma unroll
    for (int o = 32; o > 0; o >>= 1) v += __shfl_down(v, o);
    return v;
}

// ---- init: pred = sigmoid(logits) -> buf[0..32), target copy -> buf[32..64),
//      plus per-image dice partial sums (inter, sum_pred, sum_target) ----
__global__ __launch_bounds__(256) void init_kernel(
    const float* __restrict__ logits, const float* __restrict__ target,
    float* __restrict__ buf, double* __restrict__ sums)
{
    const int img = blockIdx.x >> 10;            // 1024 blocks per image
    const int idx = blockIdx.x * 256 + threadIdx.x;
    float a, b;
    if (img < NPRED) {
        float p = 1.0f / (1.0f + __expf(-logits[idx]));
        float t = target[idx];
        buf[idx] = p;
        a = p * t; b = p;
    } else {
        float t = target[idx - NPRED * IMG];
        buf[idx] = t;
        a = t; b = 0.0f;
    }
    __shared__ float red[8];
    a = wsum(a); b = wsum(b);
    const int lane = threadIdx.x & 63, w = threadIdx.x >> 6;
    if (lane == 0) { red[w] = a; red[4 + w] = b; }
    __syncthreads();
    if (threadIdx.x == 0) {
        double A = (double)red[0] + red[1] + red[2] + red[3];
        double Bs = (double)red[4] + red[5] + red[6] + red[7];
        if (img < NPRED) { atomicAdd(&sums[img], A); atomicAdd(&sums[32 + img], Bs); }
        else atomicAdd(&sums[64 + (img - NPRED)], A);
    }
}

// hmin over x for 6 columns (x = X-1 .. X+4) of LDS row r; 3 aligned b128 reads.
__device__ __forceinline__ void hmin_row(const float* __restrict__ s, int r, int tx, float h[6])
{
    const float* row = s + r * SPITCH + 4 * tx;  // quad base = x-4
    float4 q0 = *(const float4*)(row);           // x-4 .. x-1
    float4 q1 = *(const float4*)(row + 4);       // x   .. x+3
    float4 q2 = *(const float4*)(row + 8);       // x+4 .. x+7
    h[0] = fminf(q0.z, fminf(q0.w, q1.x));
    h[1] = fminf(q0.w, fminf(q1.x, q1.y));
    h[2] = fminf(q1.x, fminf(q1.y, q1.z));
    h[3] = fminf(q1.y, fminf(q1.z, q1.w));
    h[4] = fminf(q1.z, fminf(q1.w, q2.x));
    h[5] = fminf(q1.w, fminf(q2.x, q2.y));
}

// eroded row gy = vertical min of 3 hmin rows; rows/cols outside image forced to -inf
// (dilation padding semantics).
__device__ __forceinline__ void erode_combine(const float a[6], const float b[6], const float c[6],
                                              int gy, bool lo, bool ro, float e[6])
{
    const float NEG = -INFINITY;
    bool oob = (gy < 0) || (gy >= H);
#pragma unroll
    for (int i = 0; i < 6; i++) {
        float v = fminf(a[i], fminf(b[i], c[i]));
        e[i] = oob ? NEG : v;
    }
    if (lo) e[0] = NEG;
    if (ro) e[5] = NEG;
}

__device__ __forceinline__ void hmax_row(const float e[6], float hx[4], float ec[4])
{
    hx[0] = fmaxf(e[0], fmaxf(e[1], e[2]));
    hx[1] = fmaxf(e[1], fmaxf(e[2], e[3]));
    hx[2] = fmaxf(e[2], fmaxf(e[3], e[4]));
    hx[3] = fmaxf(e[3], fmaxf(e[4], e[5]));
    ec[0] = e[1]; ec[1] = e[2]; ec[2] = e[3]; ec[3] = e[4];
}

// ---- one skeletonize iteration: out = clip(s - (s - erode(s)) * dilate(erode(s)), 0, 1)
// Tile 64x64 per block, block (16,8): each thread = 4 cols (float4) x 8 rows,
// eroded computed redundantly per-thread in registers (no LDS round-trip).
__global__ __launch_bounds__(128) void skel_iter(
    const float* __restrict__ in, float* __restrict__ out)
{
    __shared__ float s[SROWS * SPITCH];
    const int img = blockIdx.z;
    const int tileX = blockIdx.x * 64;
    const int tileY = blockIdx.y * 64;
    const float* ip = in + (size_t)img * IMG;
    float* op = out + (size_t)img * IMG;
    const int tid = threadIdx.y * 16 + threadIdx.x;
    const float PINF = INFINITY;

    // load tile: rows tileY-2..tileY+65, cols tileX-4..tileX+67 (18 quads/row).
    // Each quad is fully in-image or fully out (W,H multiples of 64, quads 4-aligned).
    for (int q = tid; q < SROWS * 18; q += 128) {
        int r = q / 18;
        int c = q - r * 18;
        int gy = tileY - 2 + r;
        int gx = tileX - 4 + 4 * c;
        float4 v;
        if (gy >= 0 && gy < H && gx >= 0 && gx + 3 < W)
            v = *(const float4*)(ip + (size_t)gy * W + gx);
        else
            v = make_float4(PINF, PINF, PINF, PINF);  // +inf: neutral for erosion min
        *(float4*)(s + r * SPITCH + 4 * c) = v;
    }
    __syncthreads();

    const int tx = threadIdx.x;        // 0..15: column quad
    const int ty = threadIdx.y;        // 0..7 : 8-row strip
    const int X = tileX + 4 * tx;      // first output col
    const int k0 = ty * 8;             // first output row (tile-local)
    const int gy0 = tileY + k0;
    const int rbase = k0 + 2;          // LDS row index of gy0
    const bool lo = (X == 0);          // eroded col x=X-1 out of image
    const bool ro = (X + 4 >= W);      // eroded col x=X+4 out of image

    float hm[3][6], hx[3][4], e[6], ec_cur[4], ec_nxt[4], ecd[4];
    // prologue: hmin rows gy0-2..gy0, eroded/hmax rows gy0-1 and gy0
    hmin_row(s, rbase - 2, tx, hm[0]);
    hmin_row(s, rbase - 1, tx, hm[1]);
    hmin_row(s, rbase + 0, tx, hm[2]);
    erode_combine(hm[0], hm[1], hm[2], gy0 - 1, lo, ro, e);
    hmax_row(e, hx[0], ecd);
    hmin_row(s, rbase + 1, tx, hm[0]);
    erode_combine(hm[1], hm[2], hm[0], gy0 + 0, lo, ro, e);
    hmax_row(e, hx[1], ec_cur);

#pragma unroll
    for (int k = 0; k < 8; k++) {
        // advance: hmin row gy0+k+2, eroded/hmax row gy0+k+1
        hmin_row(s, rbase + 2 + k, tx, hm[(k + 1) % 3]);
        erode_combine(hm[(k + 2) % 3], hm[k % 3], hm[(k + 1) % 3], gy0 + k + 1, lo, ro, e);
        hmax_row(e, hx[(k + 2) % 3], ec_nxt);
        // temp = vertical max of hmax rows k-1..k+1
        float t0 = fmaxf(hx[k % 3][0], fmaxf(hx[(k + 1) % 3][0], hx[(k + 2) % 3][0]));
        float t1 = fmaxf(hx[k % 3][1], fmaxf(hx[(k + 1) % 3][1], hx[(k + 2) % 3][1]));
        float t2 = fmaxf(hx[k % 3][2], fmaxf(hx[(k + 1) % 3][2], hx[(k + 2) % 3][2]));
        float t3 = fmaxf(hx[k % 3][3], fmaxf(hx[(k + 1) % 3][3], hx[(k + 2) % 3][3]));
        float4 sc = *(const float4*)(s + (rbase + k) * SPITCH + 4 * tx + 4);
        float4 o;
        o.x = sc.x - (sc.x - ec_cur[0]) * t0;
        o.y = sc.y - (sc.y - ec_cur[1]) * t1;
        o.z = sc.z - (sc.z - ec_cur[2]) * t2;
        o.w = sc.w - (sc.w - ec_cur[3]) * t3;
        o.x = fminf(fmaxf(o.x, 0.0f), 1.0f);
        o.y = fminf(fmaxf(o.y, 0.0f), 1.0f);
        o.z = fminf(fmaxf(o.z, 0.0f), 1.0f);
        o.w = fminf(fmaxf(o.w, 0.0f), 1.0f);
        *(float4*)(op + (size_t)(gy0 + k) * W + X) = o;
        ec_cur[0] = ec_nxt[0]; ec_cur[1] = ec_nxt[1];
        ec_cur[2] = ec_nxt[2]; ec_cur[3] = ec_nxt[3];
    }
}

// ---- per-image skeleton dice partial sums ----
__global__ __launch_bounds__(256) void skel_sums(
    const float* __restrict__ buf, double* __restrict__ sums)
{
    const int img = blockIdx.x >> 10;
    const int idx = blockIdx.x * 256 + threadIdx.x;
    float p = buf[idx];
    float t = buf[idx + NPRED * IMG];
    float a = p * t, b = p, c = t;
    __shared__ float red[12];
    a = wsum(a); b = wsum(b); c = wsum(c);
    const int lane = threadIdx.x & 63, w = threadIdx.x >> 6;
    if (lane == 0) { red[w] = a; red[4 + w] = b; red[8 + w] = c; }
    __syncthreads();
    if (threadIdx.x == 0) {
        double A = (double)red[0] + red[1] + red[2] + red[3];
        double Bs = (double)red[4] + red[5] + red[6] + red[7];
        double C = (double)red[8] + red[9] + red[10] + red[11];
        atomicAdd(&sums[96 + img], A);
        atomicAdd(&sums[128 + img], Bs);
        atomicAdd(&sums[160 + img], C);
    }
}

__global__ void finalize(const double* __restrict__ sums, float* __restrict__ out)
{
    const int t = threadIdx.x;
    double d = 0.0, sd = 0.0;
    if (t < 32) {
        double inter = sums[t], sp = sums[32 + t], st = sums[64 + t];
        d = (2.0 * inter + 1e-5) / (sp + st + 1e-5);
        double i2 = sums[96 + t], sp2 = sums[128 + t], st2 = sums[160 + t];
        sd = (2.0 * i2 + 1e-5) / (sp2 + st2 + 1e-5);
    }
#pragma unroll
    for (int o = 32; o > 0; o >>= 1) { d += __shfl_down(d, o); sd += __shfl_down(sd, o); }
    if (t == 0) {
        d *= (1.0 / 32.0); sd *= (1.0 / 32.0);
        out[0] = (float)(0.5 * (1.0 - d) + 0.5 * (1.0 - sd));
        out[1] = (float)d;
        out[2] = (float)sd;
    }
}

extern "C" void kernel_launch(void* const* d_in, const int* in_sizes, int n_in,
                              void* d_out, int out_size, void* d_ws, size_t ws_size,
                              hipStream_t stream) {
    (void)in_sizes; (void)n_in; (void)out_size; (void)ws_size;
    const float* logits = (const float*)d_in[0];
    const float* target = (const float*)d_in[1];
    float* out = (float*)d_out;
    float* buf0 = (float*)d_ws;                          // 64 * 262144 floats
    float* buf1 = buf0 + (size_t)NIMG * IMG;             // same
    double* sums = (double*)(buf1 + (size_t)NIMG * IMG); // 192 doubles

    hipMemsetAsync(sums, 0, 192 * sizeof(double), stream);
    init_kernel<<<(NIMG * IMG) / 256, 256, 0, stream>>>(logits, target, buf0, sums);

    float* cur = buf0;
    float* nxt = buf1;
    for (int i = 0; i < ITERS; i++) {
        dim3 g(W / 64, H / 64, NIMG);
        dim3 blk(16, 8, 1);
        skel_iter<<<g, blk, 0, stream>>>(cur, nxt);
        float* tp = cur; cur = nxt; nxt = tp;
    }
    skel_sums<<<(NPRED * IMG) / 256, 256, 0, stream>>>(cur, sums);
    finalize<<<1, 64, 0, stream>>>(sums, out);
}

// Round 2
// 466.543 us; speedup vs baseline: 2.2706x; 2.2706x over previous
//
#include <hip/hip_runtime.h>
#include <math.h>

// clDice loss: sigmoid + dice + 10x soft-skeletonize (min3x3 -> max3x3 -> blend -> clip)
// on 32x1x512x512 pred & target, then skeleton dice. Output: [loss, dice, skel_dice].
// R1: replaced contended double atomicAdd (CAS-loop storm, init 373us @ 4% HBM)
//     with per-block partial writes + tiny reduction kernels. No atomics anywhere.

#define H 512
#define W 512
#define IMG (H * W)        // 262144
#define NIMG 64            // 32 pred + 32 target stacked
#define NPRED 32
#define ITERS 10

#define BLK_ELEMS 2048     // elements per reduction block (256 thr x 2 float4 sweeps)
#define PPI (IMG / BLK_ELEMS)          // 128 partial blocks per image
#define INIT_BLOCKS (NIMG * IMG / BLK_ELEMS)   // 8192
#define SUMS_BLOCKS (NPRED * IMG / BLK_ELEMS)  // 4096

#define SPITCH 72          // LDS row pitch (floats): 4 halo + 64 + 4 (16B-aligned)
#define SROWS 68           // 2 + 64 + 2

__device__ __forceinline__ float wsum(float v) {
#pragma unroll
    for (int o = 32; o > 0; o >>= 1) v += __shfl_down(v, o);
    return v;
}

// ---- init: pred = sigmoid(logits) -> buf[0..32), target copy -> buf[32..64),
//      per-block dice partials (no atomics): parts0 = inter|sum_t, parts1 = sum_pred ----
__global__ __launch_bounds__(256) void init_kernel(
    const float* __restrict__ logits, const float* __restrict__ target,
    float* __restrict__ buf, float* __restrict__ parts0, float* __restrict__ parts1)
{
    const int bid = blockIdx.x;
    const int img = bid >> 7;                 // PPI=128 blocks per image
    const int base = bid * BLK_ELEMS;
    float a = 0.0f, b = 0.0f;
    if (img < NPRED) {
#pragma unroll
        for (int sweep = 0; sweep < 2; sweep++) {
            int idx = base + sweep * 1024 + threadIdx.x * 4;
            float4 lg = *(const float4*)(logits + idx);
            float4 tg = *(const float4*)(target + idx);
            float4 p;
            p.x = 1.0f / (1.0f + __expf(-lg.x));
            p.y = 1.0f / (1.0f + __expf(-lg.y));
            p.z = 1.0f / (1.0f + __expf(-lg.z));
            p.w = 1.0f / (1.0f + __expf(-lg.w));
            *(float4*)(buf + idx) = p;
            a += p.x * tg.x + p.y * tg.y + p.z * tg.z + p.w * tg.w;
            b += p.x + p.y + p.z + p.w;
        }
    } else {
#pragma unroll
        for (int sweep = 0; sweep < 2; sweep++) {
            int idx = base + sweep * 1024 + threadIdx.x * 4;
            float4 tg = *(const float4*)(target + idx - NPRED * IMG);
            *(float4*)(buf + idx) = tg;
            a += tg.x + tg.y + tg.z + tg.w;
        }
    }
    __shared__ float red[8];
    a = wsum(a); b = wsum(b);
    const int lane = threadIdx.x & 63, w = threadIdx.x >> 6;
    if (lane == 0) { red[w] = a; red[4 + w] = b; }
    __syncthreads();
    if (threadIdx.x == 0) {
        parts0[bid] = red[0] + red[1] + red[2] + red[3];
        parts1[bid] = red[4] + red[5] + red[6] + red[7];
    }
}

// hmin over x for 6 columns (x = X-1 .. X+4) of LDS row r; 3 aligned b128 reads.
__device__ __forceinline__ void hmin_row(const float* __restrict__ s, int r, int tx, float h[6])
{
    const float* row = s + r * SPITCH + 4 * tx;  // quad base = x-4
    float4 q0 = *(const float4*)(row);
    float4 q1 = *(const float4*)(row + 4);
    float4 q2 = *(const float4*)(row + 8);
    h[0] = fminf(q0.z, fminf(q0.w, q1.x));
    h[1] = fminf(q0.w, fminf(q1.x, q1.y));
    h[2] = fminf(q1.x, fminf(q1.y, q1.z));
    h[3] = fminf(q1.y, fminf(q1.z, q1.w));
    h[4] = fminf(q1.z, fminf(q1.w, q2.x));
    h[5] = fminf(q1.w, fminf(q2.x, q2.y));
}

__device__ __forceinline__ void erode_combine(const float a[6], const float b[6], const float c[6],
                                              int gy, bool lo, bool ro, float e[6])
{
    const float NEG = -INFINITY;
    bool oob = (gy < 0) || (gy >= H);
#pragma unroll
    for (int i = 0; i < 6; i++) {
        float v = fminf(a[i], fminf(b[i], c[i]));
        e[i] = oob ? NEG : v;
    }
    if (lo) e[0] = NEG;
    if (ro) e[5] = NEG;
}

__device__ __forceinline__ void hmax_row(const float e[6], float hx[4], float ec[4])
{
    hx[0] = fmaxf(e[0], fmaxf(e[1], e[2]));
    hx[1] = fmaxf(e[1], fmaxf(e[2], e[3]));
    hx[2] = fmaxf(e[2], fmaxf(e[3], e[4]));
    hx[3] = fmaxf(e[3], fmaxf(e[4], e[5]));
    ec[0] = e[1]; ec[1] = e[2]; ec[2] = e[3]; ec[3] = e[4];
}

// ---- one skeletonize iteration: out = clip(s - (s - erode(s)) * dilate(erode(s)), 0, 1)
__global__ __launch_bounds__(128) void skel_iter(
    const float* __restrict__ in, float* __restrict__ out)
{
    __shared__ float s[SROWS * SPITCH];
    const int img = blockIdx.z;
    const int tileX = blockIdx.x * 64;
    const int tileY = blockIdx.y * 64;
    const float* ip = in + (size_t)img * IMG;
    float* op = out + (size_t)img * IMG;
    const int tid = threadIdx.y * 16 + threadIdx.x;
    const float PINF = INFINITY;

    for (int q = tid; q < SROWS * 18; q += 128) {
        int r = q / 18;
        int c = q - r * 18;
        int gy = tileY - 2 + r;
        int gx = tileX - 4 + 4 * c;
        float4 v;
        if (gy >= 0 && gy < H && gx >= 0 && gx + 3 < W)
            v = *(const float4*)(ip + (size_t)gy * W + gx);
        else
            v = make_float4(PINF, PINF, PINF, PINF);  // +inf: neutral for erosion min
        *(float4*)(s + r * SPITCH + 4 * c) = v;
    }
    __syncthreads();

    const int tx = threadIdx.x;
    const int ty = threadIdx.y;
    const int X = tileX + 4 * tx;
    const int k0 = ty * 8;
    const int gy0 = tileY + k0;
    const int rbase = k0 + 2;
    const bool lo = (X == 0);
    const bool ro = (X + 4 >= W);

    float hm[3][6], hx[3][4], e[6], ec_cur[4], ec_nxt[4], ecd[4];
    hmin_row(s, rbase - 2, tx, hm[0]);
    hmin_row(s, rbase - 1, tx, hm[1]);
    hmin_row(s, rbase + 0, tx, hm[2]);
    erode_combine(hm[0], hm[1], hm[2], gy0 - 1, lo, ro, e);
    hmax_row(e, hx[0], ecd);
    hmin_row(s, rbase + 1, tx, hm[0]);
    erode_combine(hm[1], hm[2], hm[0], gy0 + 0, lo, ro, e);
    hmax_row(e, hx[1], ec_cur);

#pragma unroll
    for (int k = 0; k < 8; k++) {
        hmin_row(s, rbase + 2 + k, tx, hm[(k + 1) % 3]);
        erode_combine(hm[(k + 2) % 3], hm[k % 3], hm[(k + 1) % 3], gy0 + k + 1, lo, ro, e);
        hmax_row(e, hx[(k + 2) % 3], ec_nxt);
        float t0 = fmaxf(hx[k % 3][0], fmaxf(hx[(k + 1) % 3][0], hx[(k + 2) % 3][0]));
        float t1 = fmaxf(hx[k % 3][1], fmaxf(hx[(k + 1) % 3][1], hx[(k + 2) % 3][1]));
        float t2 = fmaxf(hx[k % 3][2], fmaxf(hx[(k + 1) % 3][2], hx[(k + 2) % 3][2]));
        float t3 = fmaxf(hx[k % 3][3], fmaxf(hx[(k + 1) % 3][3], hx[(k + 2) % 3][3]));
        float4 sc = *(const float4*)(s + (rbase + k) * SPITCH + 4 * tx + 4);
        float4 o;
        o.x = sc.x - (sc.x - ec_cur[0]) * t0;
        o.y = sc.y - (sc.y - ec_cur[1]) * t1;
        o.z = sc.z - (sc.z - ec_cur[2]) * t2;
        o.w = sc.w - (sc.w - ec_cur[3]) * t3;
        o.x = fminf(fmaxf(o.x, 0.0f), 1.0f);
        o.y = fminf(fmaxf(o.y, 0.0f), 1.0f);
        o.z = fminf(fmaxf(o.z, 0.0f), 1.0f);
        o.w = fminf(fmaxf(o.w, 0.0f), 1.0f);
        *(float4*)(op + (size_t)(gy0 + k) * W + X) = o;
        ec_cur[0] = ec_nxt[0]; ec_cur[1] = ec_nxt[1];
        ec_cur[2] = ec_nxt[2]; ec_cur[3] = ec_nxt[3];
    }
}

// ---- per-block skeleton dice partials (no atomics) ----
__global__ __launch_bounds__(256) void skel_sums(
    const float* __restrict__ buf,
    float* __restrict__ pA, float* __restrict__ pB, float* __restrict__ pC)
{
    const int bid = blockIdx.x;
    const int base = bid * BLK_ELEMS;
    float a = 0.0f, b = 0.0f, c = 0.0f;
#pragma unroll
    for (int sweep = 0; sweep < 2; sweep++) {
        int idx = base + sweep * 1024 + threadIdx.x * 4;
        float4 p = *(const float4*)(buf + idx);
        float4 t = *(const float4*)(buf + idx + NPRED * IMG);
        a += p.x * t.x + p.y * t.y + p.z * t.z + p.w * t.w;
        b += p.x + p.y + p.z + p.w;
        c += t.x + t.y + t.z + t.w;
    }
    __shared__ float red[12];
    a = wsum(a); b = wsum(b); c = wsum(c);
    const int lane = threadIdx.x & 63, w = threadIdx.x >> 6;
    if (lane == 0) { red[w] = a; red[4 + w] = b; red[8 + w] = c; }
    __syncthreads();
    if (threadIdx.x == 0) {
        pA[bid] = red[0] + red[1] + red[2] + red[3];
        pB[bid] = red[4] + red[5] + red[6] + red[7];
        pC[bid] = red[8] + red[9] + red[10] + red[11];
    }
}

// ---- per-image dice from partials: block i -> dices[i] (plain), dices[32+i] (skel) ----
__global__ __launch_bounds__(128) void finalize_img(
    const float* __restrict__ parts0, const float* __restrict__ parts1,
    const float* __restrict__ pA, const float* __restrict__ pB, const float* __restrict__ pC,
    float* __restrict__ dices)
{
    const int i = blockIdx.x;        // image
    const int t = threadIdx.x;       // 0..127 over PPI=128 partials
    float inter = parts0[i * PPI + t];
    float sp    = parts1[i * PPI + t];
    float st    = parts0[(NPRED + i) * PPI + t];
    float i2 = pA[i * PPI + t];
    float sp2 = pB[i * PPI + t];
    float st2 = pC[i * PPI + t];
    __shared__ float red[12];
    inter = wsum(inter); sp = wsum(sp); st = wsum(st);
    i2 = wsum(i2); sp2 = wsum(sp2); st2 = wsum(st2);
    const int lane = t & 63, w = t >> 6;
    if (lane == 0) {
        red[w] = inter; red[2 + w] = sp; red[4 + w] = st;
        red[6 + w] = i2; red[8 + w] = sp2; red[10 + w] = st2;
    }
    __syncthreads();
    if (t == 0) {
        double I = (double)red[0] + red[1];
        double SP = (double)red[2] + red[3];
        double ST = (double)red[4] + red[5];
        double I2 = (double)red[6] + red[7];
        double SP2 = (double)red[8] + red[9];
        double ST2 = (double)red[10] + red[11];
        dices[i] = (float)((2.0 * I + 1e-5) / (SP + ST + 1e-5));
        dices[32 + i] = (float)((2.0 * I2 + 1e-5) / (SP2 + ST2 + 1e-5));
    }
}

__global__ void finalize_out(const float* __restrict__ dices, float* __restrict__ out)
{
    const int t = threadIdx.x;
    double d = 0.0, sd = 0.0;
    if (t < 32) { d = dices[t]; sd = dices[32 + t]; }
#pragma unroll
    for (int o = 32; o > 0; o >>= 1) { d += __shfl_down(d, o); sd += __shfl_down(sd, o); }
    if (t == 0) {
        d *= (1.0 / 32.0); sd *= (1.0 / 32.0);
        out[0] = (float)(0.5 * (1.0 - d) + 0.5 * (1.0 - sd));
        out[1] = (float)d;
        out[2] = (float)sd;
    }
}

extern "C" void kernel_launch(void* const* d_in, const int* in_sizes, int n_in,
                              void* d_out, int out_size, void* d_ws, size_t ws_size,
                              hipStream_t stream) {
    (void)in_sizes; (void)n_in; (void)out_size; (void)ws_size;
    const float* logits = (const float*)d_in[0];
    const float* target = (const float*)d_in[1];
    float* out = (float*)d_out;
    float* buf0 = (float*)d_ws;                          // 64 * 262144 floats
    float* buf1 = buf0 + (size_t)NIMG * IMG;
    float* parts0 = buf1 + (size_t)NIMG * IMG;           // 8192
    float* parts1 = parts0 + INIT_BLOCKS;                // 8192
    float* pA = parts1 + INIT_BLOCKS;                    // 4096
    float* pB = pA + SUMS_BLOCKS;                        // 4096
    float* pC = pB + SUMS_BLOCKS;                        // 4096
    float* dices = pC + SUMS_BLOCKS;                     // 64

    init_kernel<<<INIT_BLOCKS, 256, 0, stream>>>(logits, target, buf0, parts0, parts1);

    float* cur = buf0;
    float* nxt = buf1;
    for (int i = 0; i < ITERS; i++) {
        dim3 g(W / 64, H / 64, NIMG);
        dim3 blk(16, 8, 1);
        skel_iter<<<g, blk, 0, stream>>>(cur, nxt);
        float* tp = cur; cur = nxt; nxt = tp;
    }
    skel_sums<<<SUMS_BLOCKS, 256, 0, stream>>>(cur, pA, pB, pC);
    finalize_img<<<NPRED, 128, 0, stream>>>(parts0, parts1, pA, pB, pC, dices);
    finalize_out<<<1, 64, 0, stream>>>(dices, out);
}